// Round 14
// baseline (197.367 us; speedup 1.0000x reference)
//
#include <hip/hip_runtime.h>
#include <math.h>

// ---------------------------------------------------------------- types
typedef __bf16 bf16_t;
typedef bf16_t bf16x8 __attribute__((ext_vector_type(8)));
typedef float f32x4 __attribute__((ext_vector_type(4)));
typedef unsigned int u32x4 __attribute__((ext_vector_type(4)));

#define S_LEN 2048
#define NHEAD 16
#define DHEAD 64
#define DMODEL 1024
#define BATCH 2

__device__ __forceinline__ float bf2f(unsigned short u) {
    unsigned int x = ((unsigned int)u) << 16;
    return __builtin_bit_cast(float, x);
}
__device__ __forceinline__ unsigned short f2bf(float f) {
    unsigned int x = __builtin_bit_cast(unsigned int, f);
    x += 0x7fffu + ((x >> 16) & 1u);          // RNE
    return (unsigned short)(x >> 16);
}

// async global->LDS, 16B per lane. LDS dest = wave-uniform base + lane*16.
__device__ __forceinline__ void glds16(const void* g, void* l) {
    __builtin_amdgcn_global_load_lds(
        (__attribute__((address_space(1))) void*)g,
        (__attribute__((address_space(3))) void*)l,
        16, 0, 0);
}

#define SCALE2 0.1803368801f   // 1/sqrt(64) * log2(e), folded into Q at qkv epilogue

// ---------------------------------------------------------------- fp32 -> bf16 convert (r6-verified)
__global__ __launch_bounds__(256) void cvt_kernel(
    const float* __restrict__ x,  const float* __restrict__ wq,
    const float* __restrict__ wk, const float* __restrict__ wv,
    const float* __restrict__ wo,
    unsigned short* __restrict__ xb,  unsigned short* __restrict__ wqb,
    unsigned short* __restrict__ wkb, unsigned short* __restrict__ wvb,
    unsigned short* __restrict__ wob)
{
    const int bid = blockIdx.x;          // 0..8191
    const float* s;
    unsigned short* d;
    int i;
    if (bid < 4096) {
        s = x; d = xb; i = bid * 256 + threadIdx.x;
    } else {
        const int k = (bid - 4096) >> 10;           // 0..3
        s = (k == 0) ? wq : (k == 1) ? wk : (k == 2) ? wv : wo;
        d = (k == 0) ? wqb : (k == 1) ? wkb : (k == 2) ? wvb : wob;
        i = ((bid - 4096) & 1023) * 256 + threadIdx.x;
    }
    float4 v = ((const float4*)s)[i];
    ushort4 o;
    o.x = f2bf(v.x); o.y = f2bf(v.y); o.z = f2bf(v.z); o.w = f2bf(v.w);
    ((ushort4*)d)[i] = o;
}

// ---------------------------------------------------------------- RoPE cos/sin table (r6-verified)
__global__ __launch_bounds__(256) void rope_table_kernel(float2* __restrict__ tab)
{
    const int gid = blockIdx.x * 256 + threadIdx.x;   // 65536
    const int s = gid >> 5, d = gid & 31;
    const float freq = exp2f(-0.4152410119f * (float)d);
    const float ang = (float)s * freq;
    tab[gid] = make_float2(cosf(ang), sinf(ang));
}

// ---------------------------------------------------------------- fused QKV GEMM
// Round-24: single-buffer 2-barrier loop (m97/r6 structure) + r10's verified
// XOR swizzle. Rationale: dbuf cost 64 KB LDS -> 2 blocks/CU; m97 evidence
// (912 TF at 32 KB, 3 blocks/CU; m99/m100: explicit dbuf adds nothing once
// cross-block wave overlap exists) says residency > explicit prefetch.
// 32 KB LDS + VGPR ~88 -> 4-5 blocks/CU. __syncthreads drains vmcnt (glds).
__global__ __launch_bounds__(256) void qkv_gemm_kernel(
    const unsigned short* __restrict__ xb,
    const unsigned short* __restrict__ wqb, const unsigned short* __restrict__ wkb,
    const unsigned short* __restrict__ wvb,
    const float* __restrict__ bq, const float* __restrict__ bk, const float* __restrict__ bv,
    const float2* __restrict__ tab,
    unsigned short* __restrict__ Qr, unsigned short* __restrict__ Kr,
    unsigned short* __restrict__ VT)
{
    __shared__ __align__(16) unsigned short As[128 * 64];
    __shared__ __align__(16) unsigned short Bs[128 * 64];

    const int which = blockIdx.x >> 3;
    const int bn = (blockIdx.x & 7) * 128;
    const int bm = blockIdx.y * 128;
    const unsigned short* W = (which == 0) ? wqb : (which == 1) ? wkb : wvb;
    const float* bias       = (which == 0) ? bq  : (which == 1) ? bk  : bv;

    const int tid  = threadIdx.x;
    const int lane = tid & 63;
    const int w    = tid >> 6;
    const int quad = lane >> 4;
    const int l16  = lane & 15;
    const int wm   = (w >> 1) * 64;
    const int wn   = (w & 1) * 64;

    f32x4 acc[4][4];
#pragma unroll
    for (int i = 0; i < 4; ++i)
#pragma unroll
        for (int j = 0; j < 4; ++j)
            acc[i][j] = f32x4{0.f, 0.f, 0.f, 0.f};

    const unsigned short* ga0 = xb + (size_t)bm * DMODEL;
    const unsigned short* gb0 = W  + (size_t)bn * DMODEL;

    for (int k0 = 0; k0 < DMODEL; k0 += 64) {
#pragma unroll
        for (int i_ = 0; i_ < 4; ++i_) {
            const int ck = tid + i_ * 256;
            const int kr = ck >> 3, kc = ck & 7;
            glds16(ga0 + (size_t)kr * DMODEL + k0 + ((kc ^ (kr & 7)) * 8), &As[ck * 8]);
            glds16(gb0 + (size_t)kr * DMODEL + k0 + ((kc ^ (kr & 7)) * 8), &Bs[ck * 8]);
        }
        __syncthreads();   // drains vmcnt: buf staged for all waves

        bf16x8 aF[2][4], bF[2][4];
#pragma unroll
        for (int ks = 0; ks < 2; ++ks)
#pragma unroll
            for (int t = 0; t < 4; ++t) {
                const int rowa = wm + t * 16 + l16;
                const int rowb = wn + t * 16 + l16;
                const int cb = ((ks * 4 + quad) ^ (l16 & 7)) * 8;
                aF[ks][t] = *(const bf16x8*)(&As[rowa * 64 + cb]);
                bF[ks][t] = *(const bf16x8*)(&Bs[rowb * 64 + cb]);
            }
#pragma unroll
        for (int ks = 0; ks < 2; ++ks)
#pragma unroll
            for (int mt = 0; mt < 4; ++mt)
#pragma unroll
                for (int nt = 0; nt < 4; ++nt)
                    acc[mt][nt] = __builtin_amdgcn_mfma_f32_16x16x32_bf16(
                        aF[ks][mt], bF[ks][nt], acc[mt][nt], 0, 0, 0);
        __syncthreads();   // reads done before next stage overwrites
    }

    // ---- epilogue (r6-verified)
    if (which < 2) {
        unsigned short* Y = (which == 0) ? Qr : Kr;
        const float qscale = (which == 0) ? SCALE2 : 1.0f;
#pragma unroll
        for (int mt = 0; mt < 4; ++mt) {
            const int row0 = bm + wm + mt * 16 + quad * 4;
#pragma unroll
            for (int nt = 0; nt < 2; ++nt) {
                const int d   = nt * 16 + l16;       // 0..31 within head
                const int col = bn + wn + nt * 16 + l16;
                const float b1 = bias[col];
                const float b2 = bias[col + 32];
#pragma unroll
                for (int r = 0; r < 4; ++r) {
                    const int row = row0 + r;
                    const int s = row & (S_LEN - 1);
                    const float2 cs = tab[s * 32 + d];
                    const float x1 = acc[mt][nt][r] + b1;
                    const float x2 = acc[mt][nt + 2][r] + b2;
                    Y[(size_t)row * DMODEL + col]      = f2bf((x1 * cs.x - x2 * cs.y) * qscale);
                    Y[(size_t)row * DMODEL + col + 32] = f2bf((x2 * cs.x + x1 * cs.y) * qscale);
                }
            }
        }
    } else {
#pragma unroll
        for (int mt = 0; mt < 4; ++mt) {
            const int row0 = bm + wm + mt * 16 + quad * 4;
            const int bb = row0 >> 11, s0 = row0 & (S_LEN - 1);
            const int h = (bn + wn) >> 6;
#pragma unroll
            for (int nt = 0; nt < 4; ++nt) {
                const int d = nt * 16 + l16;
                const float bv2 = bias[bn + wn + nt * 16 + l16];
                unsigned short pk[4];
#pragma unroll
                for (int r = 0; r < 4; ++r)
                    pk[r] = f2bf(acc[mt][nt][r] + bv2);
                *(uint2*)(&VT[((size_t)(bb * NHEAD + h) * DHEAD + d) * S_LEN + s0]) =
                    *(const uint2*)pk;
            }
        }
    }
}

// ---------------------------------------------------------------- attention (r13-verified, byte-identical)
// 3-deep LDS pipeline, one barrier per stage; KVBLK=64, 4-wave blocks,
// in-register P via swapped QK^T. 49.1 us, 0 conflicts, FETCH 12.4 MB.
__global__ __launch_bounds__(256) void attn_kernel(
    const unsigned short* __restrict__ Q, const unsigned short* __restrict__ K,
    const unsigned short* __restrict__ VT, unsigned short* __restrict__ O)
{
    const int j  = blockIdx.x;          // 0..1023
    const int bh = j & 31;
    const int qs = j >> 5;              // 0..31
    const int b  = bh >> 4, h = bh & 15;
    const int oc = qs >> 3, oo = qs & 7;
    const int qt64 = (oc == 0) ? (31 - oo) : (oc == 1) ? oo
                   : (oc == 2) ? (23 - oo) : (8 + oo);   // per-CU octet sum = 62

    const int tid  = threadIdx.x;
    const int w    = tid >> 6;          // 0..3
    const int lane = tid & 63;
    const int quad = lane >> 4;
    const int l16  = lane & 15;

    __shared__ __align__(16) unsigned short Ks[3][64 * 64];   // [kpos][dh]  swizzled
    __shared__ __align__(16) unsigned short Vt[3][64 * 64];   // [dh][kpos] swizzled

    const int q0 = qt64 * 64;
    const unsigned short* Qb = Q  + (size_t)b * S_LEN * DMODEL + h * DHEAD;
    const unsigned short* Kb = K  + (size_t)b * S_LEN * DMODEL + h * DHEAD;
    const unsigned short* Vh = VT + ((size_t)(b * NHEAD + h)) * DHEAD * S_LEN;

    // Q fragment (B-operand of swapped QK^T): rows q0 + w*16 + l16
    const int qrow = q0 + w * 16 + l16;
    const bf16x8 qf0 = *(const bf16x8*)(Qb + (size_t)qrow * DMODEL + quad * 8);
    const bf16x8 qf1 = *(const bf16x8*)(Qb + (size_t)qrow * DMODEL + 32 + quad * 8);

    f32x4 o[4];
#pragma unroll
    for (int i = 0; i < 4; ++i) o[i] = f32x4{0.f, 0.f, 0.f, 0.f};
    float l_acc = 0.f;

    const int nkt = qt64 + 1;   // 64-wide k-tiles covering kpos <= q0+63

#define STAGE(bs, kt_) do {                                                        \
        _Pragma("unroll")                                                          \
        for (int i_ = 0; i_ < 2; ++i_) {                                           \
            const int ck = tid + i_ * 256;                                         \
            const int krow = ck >> 3, kc = ck & 7;                                 \
            glds16(Kb + (size_t)((kt_) * 64 + krow) * DMODEL + ((kc ^ (krow & 7)) * 8), \
                   &Ks[bs][ck * 8]);                                               \
            glds16(Vh + (size_t)krow * S_LEN + (kt_) * 64 + ((kc ^ (krow & 7)) * 8), \
                   &Vt[bs][ck * 8]);                                               \
        }                                                                          \
    } while (0)

    STAGE(0, 0);
    if (nkt > 1) STAGE(1, 1);

    for (int kt = 0; kt < nkt; ++kt) {
        const int cur = kt % 3;

        // buf[cur]'s 4 loads were issued >=2 stages ago; only STAGE(kt+1)'s
        // 4 are newer -> vmcnt(4) proves buf[cur] landed (0 on last stage).
        if (kt + 1 < nkt) {
            asm volatile("s_waitcnt vmcnt(4)" ::: "memory");
        } else {
            asm volatile("s_waitcnt vmcnt(0)" ::: "memory");
        }
        __builtin_amdgcn_s_barrier();   // single barrier: buf[cur] ready, and
                                        // buf[(kt+2)%3]'s readers (stage kt-1)
                                        // are all past this point.
        if (kt + 2 < nkt) STAGE((kt + 2) % 3, kt + 2);

        const bool diag = (kt == qt64);
        // wave w's rows see kpos(tile-local) <= w*16+15 on diag; round to 32.
        const int ntmax = diag ? ((w & ~1) + 2) : 4;
        const int cmax  = ntmax >> 1;

        // ---- scores (swapped): lane: q=l16, kpos = kt*64 + nt*16 + quad*4 + r
        f32x4 sc[4];
#pragma unroll
        for (int nt = 0; nt < 4; ++nt) {
            if (nt >= ntmax) break;
            const int row = nt * 16 + l16;
            const bf16x8 kf0 = *(const bf16x8*)(&Ks[cur][row * 64 + ((quad ^ (l16 & 7)) * 8)]);
            const bf16x8 kf1 = *(const bf16x8*)(&Ks[cur][row * 64 + (((4 + quad) ^ (l16 & 7)) * 8)]);
            f32x4 a = f32x4{0.f, 0.f, 0.f, 0.f};
            a = __builtin_amdgcn_mfma_f32_16x16x32_bf16(kf0, qf0, a, 0, 0, 0);
            a = __builtin_amdgcn_mfma_f32_16x16x32_bf16(kf1, qf1, a, 0, 0, 0);
            sc[nt] = a;
        }

        if (diag) {   // mask kpos > qpos; tile-local kpos = nt*16 + quad*4 + r
            const int thr = q0 + w * 16 + l16 - kt * 64 - quad * 4;
#pragma unroll
            for (int nt = 0; nt < 4; ++nt) {
                if (nt >= ntmax) break;
#pragma unroll
                for (int r = 0; r < 4; ++r)
                    if (nt * 16 + r > thr) sc[nt][r] = -INFINITY;
            }
        }

        // ---- exp2 + row-sum (lane owns one q-row: scalar accumulator)
#pragma unroll
        for (int nt = 0; nt < 4; ++nt) {
            if (nt >= ntmax) break;
#pragma unroll
            for (int r = 0; r < 4; ++r) {
                const float e = exp2f(sc[nt][r]);
                sc[nt][r] = e;
                l_acc += e;
            }
        }

        // ---- P -> PV A-frags in registers (verified r4 mapping)
        bf16x8 pA[2];
        const bool qlo = (quad < 2);
#pragma unroll
        for (int c = 0; c < 2; ++c) {
            if (c >= cmax) break;
            unsigned int s0, s1, t0, t1;
            asm("v_cvt_pk_bf16_f32 %0, %1, %2" : "=v"(s0) : "v"(sc[2*c][0]),   "v"(sc[2*c][1]));
            asm("v_cvt_pk_bf16_f32 %0, %1, %2" : "=v"(s1) : "v"(sc[2*c][2]),   "v"(sc[2*c][3]));
            asm("v_cvt_pk_bf16_f32 %0, %1, %2" : "=v"(t0) : "v"(sc[2*c+1][0]), "v"(sc[2*c+1][1]));
            asm("v_cvt_pk_bf16_f32 %0, %1, %2" : "=v"(t1) : "v"(sc[2*c+1][2]), "v"(sc[2*c+1][3]));
            const unsigned int m0 = qlo ? s0 : t0, m1 = qlo ? s1 : t1;
            const unsigned int n0 = qlo ? t0 : s0, n1 = qlo ? t1 : s1;
            const unsigned int X0 = __shfl_xor(m0, 16), X1 = __shfl_xor(m1, 16);
            const unsigned int A0 = __shfl_xor(n0, 32), A1 = __shfl_xor(n1, 32);
            const unsigned int B0 = __shfl_xor(n0, 48), B1 = __shfl_xor(n1, 48);
            u32x4 aw;
            aw[0] = qlo ? (quad == 0 ? m0 : B0) : (quad == 2 ? A0 : X0);
            aw[1] = qlo ? (quad == 0 ? m1 : B1) : (quad == 2 ? A1 : X1);
            aw[2] = qlo ? (quad == 0 ? X0 : A0) : (quad == 2 ? B0 : m0);
            aw[3] = qlo ? (quad == 0 ? X1 : A1) : (quad == 2 ? B1 : m1);
            pA[c] = __builtin_bit_cast(bf16x8, aw);
        }

#pragma unroll
        for (int nt = 0; nt < 4; ++nt) {
            const int row = nt * 16 + l16;
#pragma unroll
            for (int c = 0; c < 2; ++c) {
                if (c >= cmax) break;
                const bf16x8 vF = *(const bf16x8*)(&Vt[cur][row * 64 + (((c * 4 + quad) ^ (l16 & 7)) * 8)]);
                o[nt] = __builtin_amdgcn_mfma_f32_16x16x32_bf16(pA[c], vF, o[nt], 0, 0, 0);
            }
        }
        // no second barrier: 3-deep rotation protects buf reuse.
    }
#undef STAGE

    // ---- epilogue: row-sum reduce over quads, normalize, store
    {
        float rs = l_acc;
        rs += __shfl_xor(rs, 16);
        rs += __shfl_xor(rs, 32);       // full sum for q = l16, uniform over quads
        const float linv_row = 1.0f / rs;
        float linv[4];
#pragma unroll
        for (int r = 0; r < 4; ++r)
            linv[r] = __shfl(linv_row, quad * 4 + r);   // l for q-row = quad*4+r

        const int spos0 = q0 + w * 16 + quad * 4;
#pragma unroll
        for (int nt = 0; nt < 4; ++nt)
#pragma unroll
            for (int r = 0; r < 4; ++r) {
                const float val = o[nt][r] * linv[r];
                O[((size_t)b * S_LEN + spos0 + r) * DMODEL + h * DHEAD + nt * 16 + l16] = f2bf(val);
            }
    }
}

// ---------------------------------------------------------------- out-proj GEMM
// Single-buffer 2-barrier + XOR swizzle (same rationale as qkv). 24 KB LDS.
__global__ __launch_bounds__(256) void outproj_kernel(
    const unsigned short* __restrict__ A, const unsigned short* __restrict__ W,
    const float* __restrict__ bias, float* __restrict__ C)
{
    __shared__ __align__(16) unsigned short As[64 * 64];
    __shared__ __align__(16) unsigned short Bs[128 * 64];

    const int tid  = threadIdx.x;
    const int lane = tid & 63;
    const int w    = tid >> 6;
    const int quad = lane >> 4;
    const int l16  = lane & 15;
    const int wm   = (w >> 1) * 32;
    const int wn   = (w & 1) * 64;
    const int bm   = blockIdx.y * 64;
    const int bn   = blockIdx.x * 128;

    f32x4 acc[2][4];
#pragma unroll
    for (int i = 0; i < 2; ++i)
#pragma unroll
        for (int j = 0; j < 4; ++j)
            acc[i][j] = f32x4{0.f, 0.f, 0.f, 0.f};

    const unsigned short* ga0 = A + (size_t)bm * DMODEL;
    const unsigned short* gb0 = W + (size_t)bn * DMODEL;

    for (int k0 = 0; k0 < DMODEL; k0 += 64) {
#pragma unroll
        for (int i_ = 0; i_ < 2; ++i_) {
            const int ck = tid + i_ * 256;
            const int kr = ck >> 3, kc = ck & 7;
            glds16(ga0 + (size_t)kr * DMODEL + k0 + ((kc ^ (kr & 7)) * 8), &As[ck * 8]);
        }
#pragma unroll
        for (int i_ = 0; i_ < 4; ++i_) {
            const int ck = tid + i_ * 256;
            const int kr = ck >> 3, kc = ck & 7;
            glds16(gb0 + (size_t)kr * DMODEL + k0 + ((kc ^ (kr & 7)) * 8), &Bs[ck * 8]);
        }
        __syncthreads();

        bf16x8 aF[2][2], bF[2][4];
#pragma unroll
        for (int ks = 0; ks < 2; ++ks) {
#pragma unroll
            for (int t = 0; t < 2; ++t) {
                const int row = wm + t * 16 + l16;
                aF[ks][t] = *(const bf16x8*)(&As[row * 64 + (((ks * 4 + quad) ^ (l16 & 7)) * 8)]);
            }
#pragma unroll
            for (int t = 0; t < 4; ++t) {
                const int row = wn + t * 16 + l16;
                bF[ks][t] = *(const bf16x8*)(&Bs[row * 64 + (((ks * 4 + quad) ^ (l16 & 7)) * 8)]);
            }
        }
#pragma unroll
        for (int ks = 0; ks < 2; ++ks)
#pragma unroll
            for (int mt = 0; mt < 2; ++mt)
#pragma unroll
                for (int nt = 0; nt < 4; ++nt)
                    acc[mt][nt] = __builtin_amdgcn_mfma_f32_16x16x32_bf16(
                        aF[ks][mt], bF[ks][nt], acc[mt][nt], 0, 0, 0);
        __syncthreads();
    }

#pragma unroll
    for (int mt = 0; mt < 2; ++mt) {
        const int row0 = bm + wm + mt * 16 + quad * 4;
#pragma unroll
        for (int nt = 0; nt < 4; ++nt) {
            const int col = bn + wn + nt * 16 + l16;
            const float bv = bias[col];
#pragma unroll
            for (int r = 0; r < 4; ++r)
                C[(size_t)(row0 + r) * DMODEL + col] = acc[mt][nt][r] + bv;
        }
    }
}

// ---------------------------------------------------------------- launch
extern "C" void kernel_launch(void* const* d_in, const int* in_sizes, int n_in,
                              void* d_out, int out_size, void* d_ws, size_t ws_size,
                              hipStream_t stream) {
    const float* x  = (const float*)d_in[0];
    const float* Wq = (const float*)d_in[1];
    const float* bq = (const float*)d_in[2];
    const float* Wk = (const float*)d_in[3];
    const float* bk = (const float*)d_in[4];
    const float* Wv = (const float*)d_in[5];
    const float* bv = (const float*)d_in[6];
    const float* Wo = (const float*)d_in[7];
    const float* bo = (const float*)d_in[8];
    float* out = (float*)d_out;

    char* ws = (char*)d_ws;
    const size_t MB = 1 << 20;
    unsigned short* xb  = (unsigned short*)(ws);            //  8 MB
    unsigned short* wqb = (unsigned short*)(ws + 8  * MB);  //  2 MB each
    unsigned short* wkb = (unsigned short*)(ws + 10 * MB);
    unsigned short* wvb = (unsigned short*)(ws + 12 * MB);
    unsigned short* wob = (unsigned short*)(ws + 14 * MB);
    float2*         tab = (float2*)       (ws + 16 * MB);   // 512 KB
    unsigned short* Qr  = (unsigned short*)(ws + 17 * MB);  //  8 MB
    unsigned short* Kr  = (unsigned short*)(ws + 25 * MB);
    unsigned short* VT  = (unsigned short*)(ws + 33 * MB);
    unsigned short* AO  = (unsigned short*)(ws + 41 * MB);

    const int M = BATCH * S_LEN;   // 4096

    cvt_kernel<<<dim3(8192), 256, 0, stream>>>(
        x, Wq, Wk, Wv, Wo, xb, wqb, wkb, wvb, wob);

    rope_table_kernel<<<256, 256, 0, stream>>>(tab);

    qkv_gemm_kernel<<<dim3(24, M / 128), 256, 0, stream>>>(
        xb, wqb, wkb, wvb, bq, bk, bv, tab, Qr, Kr, VT);

    attn_kernel<<<dim3(1024), 256, 0, stream>>>(Qr, Kr, VT, AO);

    outproj_kernel<<<dim3(DMODEL / 128, M / 64), 256, 0, stream>>>(AO, wob, bo, out);
}

// Round 15
// 188.752 us; speedup vs baseline: 1.0456x; 1.0456x over previous
//
#include <hip/hip_runtime.h>
#include <math.h>

// ---------------------------------------------------------------- types
typedef __bf16 bf16_t;
typedef bf16_t bf16x8 __attribute__((ext_vector_type(8)));
typedef float f32x4 __attribute__((ext_vector_type(4)));
typedef unsigned int u32x4 __attribute__((ext_vector_type(4)));

#define S_LEN 2048
#define NHEAD 16
#define DHEAD 64
#define DMODEL 1024
#define BATCH 2

__device__ __forceinline__ float bf2f(unsigned short u) {
    unsigned int x = ((unsigned int)u) << 16;
    return __builtin_bit_cast(float, x);
}
__device__ __forceinline__ unsigned short f2bf(float f) {
    unsigned int x = __builtin_bit_cast(unsigned int, f);
    x += 0x7fffu + ((x >> 16) & 1u);          // RNE
    return (unsigned short)(x >> 16);
}

// async global->LDS, 16B per lane. LDS dest = wave-uniform base + lane*16.
__device__ __forceinline__ void glds16(const void* g, void* l) {
    __builtin_amdgcn_global_load_lds(
        (__attribute__((address_space(1))) void*)g,
        (__attribute__((address_space(3))) void*)l,
        16, 0, 0);
}

#define SCALE2 0.1803368801f   // 1/sqrt(64) * log2(e), folded into Q at qkv epilogue

// ---------------------------------------------------------------- fp32 -> bf16 convert + RoPE table (fused)
// Round-25: 5 -> 4 launches (tests the ~13us/launch overhead hypothesis;
// accounted kernel time ~122us vs dur 190.7). blocks 0..4095: x;
// 4096..8191: weights; 8192..8447: rope table. Plain bounds (the r7/r8
// container kills correlate with (256,3) GEMM bounds, not this branch).
__global__ __launch_bounds__(256) void cvt_rope_kernel(
    const float* __restrict__ x,  const float* __restrict__ wq,
    const float* __restrict__ wk, const float* __restrict__ wv,
    const float* __restrict__ wo,
    unsigned short* __restrict__ xb,  unsigned short* __restrict__ wqb,
    unsigned short* __restrict__ wkb, unsigned short* __restrict__ wvb,
    unsigned short* __restrict__ wob, float2* __restrict__ tab)
{
    const int bid = blockIdx.x;          // 0..8447
    if (bid >= 8192) {
        const int gid = (bid - 8192) * 256 + threadIdx.x;   // 65536
        const int s = gid >> 5, d = gid & 31;
        const float freq = exp2f(-0.4152410119f * (float)d);
        const float ang = (float)s * freq;
        tab[gid] = make_float2(cosf(ang), sinf(ang));
        return;
    }
    const float* s;
    unsigned short* d;
    int i;
    if (bid < 4096) {
        s = x; d = xb; i = bid * 256 + threadIdx.x;
    } else {
        const int k = (bid - 4096) >> 10;           // 0..3
        s = (k == 0) ? wq : (k == 1) ? wk : (k == 2) ? wv : wo;
        d = (k == 0) ? wqb : (k == 1) ? wkb : (k == 2) ? wvb : wob;
        i = ((bid - 4096) & 1023) * 256 + threadIdx.x;
    }
    float4 v = ((const float4*)s)[i];
    ushort4 o;
    o.x = f2bf(v.x); o.y = f2bf(v.y); o.z = f2bf(v.z); o.w = f2bf(v.w);
    ((ushort4*)d)[i] = o;
}

// ---------------------------------------------------------------- fused QKV GEMM (r13-verified bytes)
// dbuf + counted vmcnt(8) + XOR swizzle. r14 falsified the single-buffer
// variant (58-60us vs ~44): with 8 glds/thread/step the syncthreads drain
// exposes full staging latency; counted vmcnt keeps loads in flight.
__global__ __launch_bounds__(256, 2) void qkv_gemm_kernel(
    const unsigned short* __restrict__ xb,
    const unsigned short* __restrict__ wqb, const unsigned short* __restrict__ wkb,
    const unsigned short* __restrict__ wvb,
    const float* __restrict__ bq, const float* __restrict__ bk, const float* __restrict__ bv,
    const float2* __restrict__ tab,
    unsigned short* __restrict__ Qr, unsigned short* __restrict__ Kr,
    unsigned short* __restrict__ VT)
{
    __shared__ __align__(16) unsigned short As[2][128 * 64];
    __shared__ __align__(16) unsigned short Bs[2][128 * 64];

    const int which = blockIdx.x >> 3;
    const int bn = (blockIdx.x & 7) * 128;
    const int bm = blockIdx.y * 128;
    const unsigned short* W = (which == 0) ? wqb : (which == 1) ? wkb : wvb;
    const float* bias       = (which == 0) ? bq  : (which == 1) ? bk  : bv;

    const int tid  = threadIdx.x;
    const int lane = tid & 63;
    const int w    = tid >> 6;
    const int quad = lane >> 4;
    const int l16  = lane & 15;
    const int wm   = (w >> 1) * 64;
    const int wn   = (w & 1) * 64;

    f32x4 acc[4][4];
#pragma unroll
    for (int i = 0; i < 4; ++i)
#pragma unroll
        for (int j = 0; j < 4; ++j)
            acc[i][j] = f32x4{0.f, 0.f, 0.f, 0.f};

    const unsigned short* ga0 = xb + (size_t)bm * DMODEL;
    const unsigned short* gb0 = W  + (size_t)bn * DMODEL;

#define QSTAGE(bs, k0_) do {                                                      \
        _Pragma("unroll")                                                         \
        for (int i_ = 0; i_ < 4; ++i_) {                                          \
            const int ck = tid + i_ * 256;                                        \
            const int kr = ck >> 3, kc = ck & 7;                                  \
            glds16(ga0 + (size_t)kr * DMODEL + (k0_) + ((kc ^ (kr & 7)) * 8),     \
                   &As[bs][ck * 8]);                                              \
            glds16(gb0 + (size_t)kr * DMODEL + (k0_) + ((kc ^ (kr & 7)) * 8),     \
                   &Bs[bs][ck * 8]);                                              \
        }                                                                         \
    } while (0)

    QSTAGE(0, 0);

    for (int kt = 0; kt < 16; ++kt) {
        const int cur = kt & 1;
        if (kt < 15) {
            QSTAGE(cur ^ 1, (kt + 1) * 64);
            asm volatile("s_waitcnt vmcnt(8)" ::: "memory");   // tile kt's 8 done
        } else {
            asm volatile("s_waitcnt vmcnt(0)" ::: "memory");
        }
        __builtin_amdgcn_s_barrier();   // barrier A: buf[cur] staged

        bf16x8 aF[2][4], bF[2][4];
#pragma unroll
        for (int ks = 0; ks < 2; ++ks)
#pragma unroll
            for (int t = 0; t < 4; ++t) {
                const int rowa = wm + t * 16 + l16;
                const int rowb = wn + t * 16 + l16;
                const int cb = ((ks * 4 + quad) ^ (l16 & 7)) * 8;
                aF[ks][t] = *(const bf16x8*)(&As[cur][rowa * 64 + cb]);
                bF[ks][t] = *(const bf16x8*)(&Bs[cur][rowb * 64 + cb]);
            }
#pragma unroll
        for (int ks = 0; ks < 2; ++ks)
#pragma unroll
            for (int mt = 0; mt < 4; ++mt)
#pragma unroll
                for (int nt = 0; nt < 4; ++nt)
                    acc[mt][nt] = __builtin_amdgcn_mfma_f32_16x16x32_bf16(
                        aF[ks][mt], bF[ks][nt], acc[mt][nt], 0, 0, 0);

        asm volatile("s_waitcnt lgkmcnt(0)" ::: "memory");
        __builtin_amdgcn_s_barrier();   // barrier B: buf[cur] reads done
    }
#undef QSTAGE

    // ---- epilogue (r6-verified)
    if (which < 2) {
        unsigned short* Y = (which == 0) ? Qr : Kr;
        const float qscale = (which == 0) ? SCALE2 : 1.0f;
#pragma unroll
        for (int mt = 0; mt < 4; ++mt) {
            const int row0 = bm + wm + mt * 16 + quad * 4;
#pragma unroll
            for (int nt = 0; nt < 2; ++nt) {
                const int d   = nt * 16 + l16;       // 0..31 within head
                const int col = bn + wn + nt * 16 + l16;
                const float b1 = bias[col];
                const float b2 = bias[col + 32];
#pragma unroll
                for (int r = 0; r < 4; ++r) {
                    const int row = row0 + r;
                    const int s = row & (S_LEN - 1);
                    const float2 cs = tab[s * 32 + d];
                    const float x1 = acc[mt][nt][r] + b1;
                    const float x2 = acc[mt][nt + 2][r] + b2;
                    Y[(size_t)row * DMODEL + col]      = f2bf((x1 * cs.x - x2 * cs.y) * qscale);
                    Y[(size_t)row * DMODEL + col + 32] = f2bf((x2 * cs.x + x1 * cs.y) * qscale);
                }
            }
        }
    } else {
#pragma unroll
        for (int mt = 0; mt < 4; ++mt) {
            const int row0 = bm + wm + mt * 16 + quad * 4;
            const int bb = row0 >> 11, s0 = row0 & (S_LEN - 1);
            const int h = (bn + wn) >> 6;
#pragma unroll
            for (int nt = 0; nt < 4; ++nt) {
                const int d = nt * 16 + l16;
                const float bv2 = bias[bn + wn + nt * 16 + l16];
                unsigned short pk[4];
#pragma unroll
                for (int r = 0; r < 4; ++r)
                    pk[r] = f2bf(acc[mt][nt][r] + bv2);
                *(uint2*)(&VT[((size_t)(bb * NHEAD + h) * DHEAD + d) * S_LEN + s0]) =
                    *(const uint2*)pk;
            }
        }
    }
}

// ---------------------------------------------------------------- attention (r13 + lv-chain split)
// 3-deep LDS pipeline, one barrier per stage; KVBLK=64, 4-wave blocks,
// in-register P via swapped QK^T. Only change vs r13: l_acc scalar ->
// f32x4 lv (4 independent add chains; 16-deep serial fadd became 4-deep;
// positive-term reassociation, harmless at tolerance).
__global__ __launch_bounds__(256) void attn_kernel(
    const unsigned short* __restrict__ Q, const unsigned short* __restrict__ K,
    const unsigned short* __restrict__ VT, unsigned short* __restrict__ O)
{
    const int j  = blockIdx.x;          // 0..1023
    const int bh = j & 31;
    const int qs = j >> 5;              // 0..31
    const int b  = bh >> 4, h = bh & 15;
    const int oc = qs >> 3, oo = qs & 7;
    const int qt64 = (oc == 0) ? (31 - oo) : (oc == 1) ? oo
                   : (oc == 2) ? (23 - oo) : (8 + oo);   // per-CU octet sum = 62

    const int tid  = threadIdx.x;
    const int w    = tid >> 6;          // 0..3
    const int lane = tid & 63;
    const int quad = lane >> 4;
    const int l16  = lane & 15;

    __shared__ __align__(16) unsigned short Ks[3][64 * 64];   // [kpos][dh]  swizzled
    __shared__ __align__(16) unsigned short Vt[3][64 * 64];   // [dh][kpos] swizzled

    const int q0 = qt64 * 64;
    const unsigned short* Qb = Q  + (size_t)b * S_LEN * DMODEL + h * DHEAD;
    const unsigned short* Kb = K  + (size_t)b * S_LEN * DMODEL + h * DHEAD;
    const unsigned short* Vh = VT + ((size_t)(b * NHEAD + h)) * DHEAD * S_LEN;

    // Q fragment (B-operand of swapped QK^T): rows q0 + w*16 + l16
    const int qrow = q0 + w * 16 + l16;
    const bf16x8 qf0 = *(const bf16x8*)(Qb + (size_t)qrow * DMODEL + quad * 8);
    const bf16x8 qf1 = *(const bf16x8*)(Qb + (size_t)qrow * DMODEL + 32 + quad * 8);

    f32x4 o[4];
#pragma unroll
    for (int i = 0; i < 4; ++i) o[i] = f32x4{0.f, 0.f, 0.f, 0.f};
    f32x4 lv = f32x4{0.f, 0.f, 0.f, 0.f};

    const int nkt = qt64 + 1;   // 64-wide k-tiles covering kpos <= q0+63

#define STAGE(bs, kt_) do {                                                        \
        _Pragma("unroll")                                                          \
        for (int i_ = 0; i_ < 2; ++i_) {                                           \
            const int ck = tid + i_ * 256;                                         \
            const int krow = ck >> 3, kc = ck & 7;                                 \
            glds16(Kb + (size_t)((kt_) * 64 + krow) * DMODEL + ((kc ^ (krow & 7)) * 8), \
                   &Ks[bs][ck * 8]);                                               \
            glds16(Vh + (size_t)krow * S_LEN + (kt_) * 64 + ((kc ^ (krow & 7)) * 8), \
                   &Vt[bs][ck * 8]);                                               \
        }                                                                          \
    } while (0)

    STAGE(0, 0);
    if (nkt > 1) STAGE(1, 1);

    for (int kt = 0; kt < nkt; ++kt) {
        const int cur = kt % 3;

        // buf[cur]'s 4 loads were issued >=2 stages ago; only STAGE(kt+1)'s
        // 4 are newer -> vmcnt(4) proves buf[cur] landed (0 on last stage).
        if (kt + 1 < nkt) {
            asm volatile("s_waitcnt vmcnt(4)" ::: "memory");
        } else {
            asm volatile("s_waitcnt vmcnt(0)" ::: "memory");
        }
        __builtin_amdgcn_s_barrier();   // single barrier: buf[cur] ready, and
                                        // buf[(kt+2)%3]'s readers (stage kt-1)
                                        // are all past this point.
        if (kt + 2 < nkt) STAGE((kt + 2) % 3, kt + 2);

        const bool diag = (kt == qt64);
        // wave w's rows see kpos(tile-local) <= w*16+15 on diag; round to 32.
        const int ntmax = diag ? ((w & ~1) + 2) : 4;
        const int cmax  = ntmax >> 1;

        // ---- scores (swapped): lane: q=l16, kpos = kt*64 + nt*16 + quad*4 + r
        f32x4 sc[4];
#pragma unroll
        for (int nt = 0; nt < 4; ++nt) {
            if (nt >= ntmax) break;
            const int row = nt * 16 + l16;
            const bf16x8 kf0 = *(const bf16x8*)(&Ks[cur][row * 64 + ((quad ^ (l16 & 7)) * 8)]);
            const bf16x8 kf1 = *(const bf16x8*)(&Ks[cur][row * 64 + (((4 + quad) ^ (l16 & 7)) * 8)]);
            f32x4 a = f32x4{0.f, 0.f, 0.f, 0.f};
            a = __builtin_amdgcn_mfma_f32_16x16x32_bf16(kf0, qf0, a, 0, 0, 0);
            a = __builtin_amdgcn_mfma_f32_16x16x32_bf16(kf1, qf1, a, 0, 0, 0);
            sc[nt] = a;
        }

        if (diag) {   // mask kpos > qpos; tile-local kpos = nt*16 + quad*4 + r
            const int thr = q0 + w * 16 + l16 - kt * 64 - quad * 4;
#pragma unroll
            for (int nt = 0; nt < 4; ++nt) {
                if (nt >= ntmax) break;
#pragma unroll
                for (int r = 0; r < 4; ++r)
                    if (nt * 16 + r > thr) sc[nt][r] = -INFINITY;
            }
        }

        // ---- exp2 + row-sum: 4 independent accumulator chains (lv[r])
#pragma unroll
        for (int nt = 0; nt < 4; ++nt) {
            if (nt >= ntmax) break;
#pragma unroll
            for (int r = 0; r < 4; ++r) {
                const float e = exp2f(sc[nt][r]);
                sc[nt][r] = e;
                lv[r] += e;
            }
        }

        // ---- P -> PV A-frags in registers (verified r4 mapping)
        bf16x8 pA[2];
        const bool qlo = (quad < 2);
#pragma unroll
        for (int c = 0; c < 2; ++c) {
            if (c >= cmax) break;
            unsigned int s0, s1, t0, t1;
            asm("v_cvt_pk_bf16_f32 %0, %1, %2" : "=v"(s0) : "v"(sc[2*c][0]),   "v"(sc[2*c][1]));
            asm("v_cvt_pk_bf16_f32 %0, %1, %2" : "=v"(s1) : "v"(sc[2*c][2]),   "v"(sc[2*c][3]));
            asm("v_cvt_pk_bf16_f32 %0, %1, %2" : "=v"(t0) : "v"(sc[2*c+1][0]), "v"(sc[2*c+1][1]));
            asm("v_cvt_pk_bf16_f32 %0, %1, %2" : "=v"(t1) : "v"(sc[2*c+1][2]), "v"(sc[2*c+1][3]));
            const unsigned int m0 = qlo ? s0 : t0, m1 = qlo ? s1 : t1;
            const unsigned int n0 = qlo ? t0 : s0, n1 = qlo ? t1 : s1;
            const unsigned int X0 = __shfl_xor(m0, 16), X1 = __shfl_xor(m1, 16);
            const unsigned int A0 = __shfl_xor(n0, 32), A1 = __shfl_xor(n1, 32);
            const unsigned int B0 = __shfl_xor(n0, 48), B1 = __shfl_xor(n1, 48);
            u32x4 aw;
            aw[0] = qlo ? (quad == 0 ? m0 : B0) : (quad == 2 ? A0 : X0);
            aw[1] = qlo ? (quad == 0 ? m1 : B1) : (quad == 2 ? A1 : X1);
            aw[2] = qlo ? (quad == 0 ? X0 : A0) : (quad == 2 ? B0 : m0);
            aw[3] = qlo ? (quad == 0 ? X1 : A1) : (quad == 2 ? B1 : m1);
            pA[c] = __builtin_bit_cast(bf16x8, aw);
        }

#pragma unroll
        for (int nt = 0; nt < 4; ++nt) {
            const int row = nt * 16 + l16;
#pragma unroll
            for (int c = 0; c < 2; ++c) {
                if (c >= cmax) break;
                const bf16x8 vF = *(const bf16x8*)(&Vt[cur][row * 64 + (((c * 4 + quad) ^ (l16 & 7)) * 8)]);
                o[nt] = __builtin_amdgcn_mfma_f32_16x16x32_bf16(pA[c], vF, o[nt], 0, 0, 0);
            }
        }
        // no second barrier: 3-deep rotation protects buf reuse.
    }
#undef STAGE

    // ---- epilogue: row-sum reduce over quads, normalize, store
    {
        float rs = (lv[0] + lv[1]) + (lv[2] + lv[3]);
        rs += __shfl_xor(rs, 16);
        rs += __shfl_xor(rs, 32);       // full sum for q = l16, uniform over quads
        const float linv_row = 1.0f / rs;
        float linv[4];
#pragma unroll
        for (int r = 0; r < 4; ++r)
            linv[r] = __shfl(linv_row, quad * 4 + r);   // l for q-row = quad*4+r

        const int spos0 = q0 + w * 16 + quad * 4;
#pragma unroll
        for (int nt = 0; nt < 4; ++nt)
#pragma unroll
            for (int r = 0; r < 4; ++r) {
                const float val = o[nt][r] * linv[r];
                O[((size_t)b * S_LEN + spos0 + r) * DMODEL + h * DHEAD + nt * 16 + l16] = f2bf(val);
            }
    }
}

// ---------------------------------------------------------------- out-proj GEMM (r13-verified bytes)
// dbuf + counted vmcnt(6) + XOR swizzle.
__global__ __launch_bounds__(256, 2) void outproj_kernel(
    const unsigned short* __restrict__ A, const unsigned short* __restrict__ W,
    const float* __restrict__ bias, float* __restrict__ C)
{
    __shared__ __align__(16) unsigned short As[2][64 * 64];
    __shared__ __align__(16) unsigned short Bs[2][128 * 64];

    const int tid  = threadIdx.x;
    const int lane = tid & 63;
    const int w    = tid >> 6;
    const int quad = lane >> 4;
    const int l16  = lane & 15;
    const int wm   = (w >> 1) * 32;
    const int wn   = (w & 1) * 64;
    const int bm   = blockIdx.y * 64;
    const int bn   = blockIdx.x * 128;

    f32x4 acc[2][4];
#pragma unroll
    for (int i = 0; i < 2; ++i)
#pragma unroll
        for (int j = 0; j < 4; ++j)
            acc[i][j] = f32x4{0.f, 0.f, 0.f, 0.f};

    const unsigned short* ga0 = A + (size_t)bm * DMODEL;
    const unsigned short* gb0 = W + (size_t)bn * DMODEL;

#define OSTAGE(bs, k0_) do {                                                      \
        _Pragma("unroll")                                                         \
        for (int i_ = 0; i_ < 2; ++i_) {                                          \
            const int ck = tid + i_ * 256;                                        \
            const int kr = ck >> 3, kc = ck & 7;                                  \
            glds16(ga0 + (size_t)kr * DMODEL + (k0_) + ((kc ^ (kr & 7)) * 8),     \
                   &As[bs][ck * 8]);                                              \
        }                                                                         \
        _Pragma("unroll")                                                         \
        for (int i_ = 0; i_ < 4; ++i_) {                                          \
            const int ck = tid + i_ * 256;                                        \
            const int kr = ck >> 3, kc = ck & 7;                                  \
            glds16(gb0 + (size_t)kr * DMODEL + (k0_) + ((kc ^ (kr & 7)) * 8),     \
                   &Bs[bs][ck * 8]);                                              \
        }                                                                         \
    } while (0)

    OSTAGE(0, 0);

    for (int kt = 0; kt < 16; ++kt) {
        const int cur = kt & 1;
        if (kt < 15) {
            OSTAGE(cur ^ 1, (kt + 1) * 64);
            asm volatile("s_waitcnt vmcnt(6)" ::: "memory");   // tile kt's 6 done
        } else {
            asm volatile("s_waitcnt vmcnt(0)" ::: "memory");
        }
        __builtin_amdgcn_s_barrier();   // barrier A: buf[cur] staged

        bf16x8 aF[2][2], bF[2][4];
#pragma unroll
        for (int ks = 0; ks < 2; ++ks) {
#pragma unroll
            for (int t = 0; t < 2; ++t) {
                const int row = wm + t * 16 + l16;
                aF[ks][t] = *(const bf16x8*)(&As[cur][row * 64 + (((ks * 4 + quad) ^ (l16 & 7)) * 8)]);
            }
#pragma unroll
            for (int t = 0; t < 4; ++t) {
                const int row = wn + t * 16 + l16;
                bF[ks][t] = *(const bf16x8*)(&Bs[cur][row * 64 + (((ks * 4 + quad) ^ (l16 & 7)) * 8)]);
            }
        }
#pragma unroll
        for (int ks = 0; ks < 2; ++ks)
#pragma unroll
            for (int mt = 0; mt < 2; ++mt)
#pragma unroll
                for (int nt = 0; nt < 4; ++nt)
                    acc[mt][nt] = __builtin_amdgcn_mfma_f32_16x16x32_bf16(
                        aF[ks][mt], bF[ks][nt], acc[mt][nt], 0, 0, 0);

        asm volatile("s_waitcnt lgkmcnt(0)" ::: "memory");
        __builtin_amdgcn_s_barrier();   // barrier B: buf[cur] reads done
    }
#undef OSTAGE

#pragma unroll
    for (int mt = 0; mt < 2; ++mt) {
        const int row0 = bm + wm + mt * 16 + quad * 4;
#pragma unroll
        for (int nt = 0; nt < 4; ++nt) {
            const int col = bn + wn + nt * 16 + l16;
            const float bv = bias[col];
#pragma unroll
            for (int r = 0; r < 4; ++r)
                C[(size_t)(row0 + r) * DMODEL + col] = acc[mt][nt][r] + bv;
        }
    }
}

// ---------------------------------------------------------------- launch
extern "C" void kernel_launch(void* const* d_in, const int* in_sizes, int n_in,
                              void* d_out, int out_size, void* d_ws, size_t ws_size,
                              hipStream_t stream) {
    const float* x  = (const float*)d_in[0];
    const float* Wq = (const float*)d_in[1];
    const float* bq = (const float*)d_in[2];
    const float* Wk = (const float*)d_in[3];
    const float* bk = (const float*)d_in[4];
    const float* Wv = (const float*)d_in[5];
    const float* bv = (const float*)d_in[6];
    const float* Wo = (const float*)d_in[7];
    const float* bo = (const float*)d_in[8];
    float* out = (float*)d_out;

    char* ws = (char*)d_ws;
    const size_t MB = 1 << 20;
    unsigned short* xb  = (unsigned short*)(ws);            //  8 MB
    unsigned short* wqb = (unsigned short*)(ws + 8  * MB);  //  2 MB each
    unsigned short* wkb = (unsigned short*)(ws + 10 * MB);
    unsigned short* wvb = (unsigned short*)(ws + 12 * MB);
    unsigned short* wob = (unsigned short*)(ws + 14 * MB);
    float2*         tab = (float2*)       (ws + 16 * MB);   // 512 KB
    unsigned short* Qr  = (unsigned short*)(ws + 17 * MB);  //  8 MB
    unsigned short* Kr  = (unsigned short*)(ws + 25 * MB);
    unsigned short* VT  = (unsigned short*)(ws + 33 * MB);
    unsigned short* AO  = (unsigned short*)(ws + 41 * MB);

    const int M = BATCH * S_LEN;   // 4096

    cvt_rope_kernel<<<dim3(8448), 256, 0, stream>>>(
        x, Wq, Wk, Wv, Wo, xb, wqb, wkb, wvb, wob, tab);

    qkv_gemm_kernel<<<dim3(24, M / 128), 256, 0, stream>>>(
        xb, wqb, wkb, wvb, bq, bk, bv, tab, Qr, Kr, VT);

    attn_kernel<<<dim3(1024), 256, 0, stream>>>(Qr, Kr, VT, AO);

    outproj_kernel<<<dim3(DMODEL / 128, M / 64), 256, 0, stream>>>(AO, wob, bo, out);
}